// Round 1
// baseline (96.517 us; speedup 1.0000x reference)
//
#include <hip/hip_runtime.h>

#define BATCH 384
#define DIM   1024
#define MARGIN_F 0.5f
#define EPS_F 1e-16f

// ---------------------------------------------------------------------------
// Kernel 1: pairwise Euclidean distances  d[i][j] = sqrt(sum_k (E[i][k]-E[j][k])^2)
// 32x32 output tile per block, 256 threads, each thread computes a 2x2 micro-tile.
// Direct difference form: exact 0 on diagonal (matches reference zero-mask).
// ---------------------------------------------------------------------------
__global__ __launch_bounds__(256) void dist_kernel(const float* __restrict__ E,
                                                   float* __restrict__ dmat) {
    __shared__ float As[32][33];   // +1 pad breaks bank conflicts on column reads
    __shared__ float Bs[32][33];

    const int tx = threadIdx.x & 15;   // 0..15 -> 2 cols each
    const int ty = threadIdx.x >> 4;   // 0..15 -> 2 rows each
    const int rb = blockIdx.y * 32;
    const int cb = blockIdx.x * 32;

    float acc00 = 0.f, acc01 = 0.f, acc10 = 0.f, acc11 = 0.f;

    const int lr = threadIdx.x >> 3;        // 0..31 row within tile
    const int lc = (threadIdx.x & 7) * 4;   // 0,4,...,28

    for (int k0 = 0; k0 < DIM; k0 += 32) {
        // cooperative load: one float4 per thread per tile
        float4 av = *(const float4*)&E[(size_t)(rb + lr) * DIM + k0 + lc];
        float4 bv = *(const float4*)&E[(size_t)(cb + lr) * DIM + k0 + lc];
        As[lr][lc + 0] = av.x; As[lr][lc + 1] = av.y;
        As[lr][lc + 2] = av.z; As[lr][lc + 3] = av.w;
        Bs[lr][lc + 0] = bv.x; Bs[lr][lc + 1] = bv.y;
        Bs[lr][lc + 2] = bv.z; Bs[lr][lc + 3] = bv.w;
        __syncthreads();

#pragma unroll
        for (int k = 0; k < 32; ++k) {
            float a0 = As[ty * 2 + 0][k];
            float a1 = As[ty * 2 + 1][k];
            float b0 = Bs[tx * 2 + 0][k];
            float b1 = Bs[tx * 2 + 1][k];
            float t;
            t = a0 - b0; acc00 += t * t;
            t = a0 - b1; acc01 += t * t;
            t = a1 - b0; acc10 += t * t;
            t = a1 - b1; acc11 += t * t;
        }
        __syncthreads();
    }

    const int r0 = rb + ty * 2, c0 = cb + tx * 2;
    dmat[(size_t)(r0 + 0) * BATCH + c0 + 0] = acc00 > 0.f ? sqrtf(acc00) : 0.f;
    dmat[(size_t)(r0 + 0) * BATCH + c0 + 1] = acc01 > 0.f ? sqrtf(acc01) : 0.f;
    dmat[(size_t)(r0 + 1) * BATCH + c0 + 0] = acc10 > 0.f ? sqrtf(acc10) : 0.f;
    dmat[(size_t)(r0 + 1) * BATCH + c0 + 1] = acc11 > 0.f ? sqrtf(acc11) : 0.f;
}

// ---------------------------------------------------------------------------
// Kernel 2: per-anchor triplet reduction.
// mask(a,p,n) = (a != p) && (lab[a]==lab[p]) && (lab[a]!=lab[n])
// (a!=n and p!=n are implied by the label inequality.)
// One block per anchor a; d-row and labels staged in LDS.
// ---------------------------------------------------------------------------
__global__ __launch_bounds__(256) void triplet_kernel(const float* __restrict__ dmat,
                                                      const int* __restrict__ labels,
                                                      double* __restrict__ acc) {
    __shared__ float drow[BATCH];
    __shared__ int   lab[BATCH];
    __shared__ float ssum[4];
    __shared__ int   spos[4];
    __shared__ int   sval[4];

    const int t = threadIdx.x;
    const int a = blockIdx.x;

    for (int i = t; i < BATCH; i += 256) {
        drow[i] = dmat[(size_t)a * BATCH + i];
        lab[i]  = labels[i];
    }
    __syncthreads();

    const int la = lab[a];
    float sum = 0.f;
    int   pos = 0, valid = 0;

    for (int p = 0; p < BATCH; ++p) {
        if (p == a || lab[p] != la) continue;   // block-uniform branch
        const float dap = drow[p];
        for (int n = t; n < BATCH; n += 256) {
            if (lab[n] != la) {
                ++valid;
                float tl = dap - drow[n] + MARGIN_F;
                if (tl > EPS_F) { sum += tl; ++pos; }
            }
        }
    }

    // wave (64-lane) shuffle reduction
#pragma unroll
    for (int off = 32; off > 0; off >>= 1) {
        sum   += __shfl_down(sum, off);
        pos   += __shfl_down(pos, off);
        valid += __shfl_down(valid, off);
    }
    const int wave = t >> 6, lane = t & 63;
    if (lane == 0) { ssum[wave] = sum; spos[wave] = pos; sval[wave] = valid; }
    __syncthreads();

    if (t == 0) {
        float s = 0.f; int p2 = 0, v = 0;
#pragma unroll
        for (int w = 0; w < 4; ++w) { s += ssum[w]; p2 += spos[w]; v += sval[w]; }
        atomicAdd(&acc[0], (double)s);
        atomicAdd(&acc[1], (double)p2);
        atomicAdd(&acc[2], (double)v);
    }
}

// ---------------------------------------------------------------------------
// Kernel 3: finalize -> (loss, num_positive, num_valid) as 3 floats
// ---------------------------------------------------------------------------
__global__ void finalize_kernel(const double* __restrict__ acc, float* __restrict__ out) {
    double s  = acc[0];
    double np = acc[1];
    double nv = acc[2];
    out[0] = (float)(s / (np + 1e-16));
    out[1] = (float)np;
    out[2] = (float)nv;
}

extern "C" void kernel_launch(void* const* d_in, const int* in_sizes, int n_in,
                              void* d_out, int out_size, void* d_ws, size_t ws_size,
                              hipStream_t stream) {
    const int*   labels = (const int*)d_in[0];
    const float* E      = (const float*)d_in[1];
    float* out = (float*)d_out;

    double* acc  = (double*)d_ws;
    float*  dmat = (float*)((char*)d_ws + 256);

    hipMemsetAsync(acc, 0, 3 * sizeof(double), stream);

    dim3 grid(BATCH / 32, BATCH / 32);
    dist_kernel<<<grid, 256, 0, stream>>>(E, dmat);
    triplet_kernel<<<BATCH, 256, 0, stream>>>(dmat, labels, acc);
    finalize_kernel<<<1, 1, 0, stream>>>(acc, out);
}

// Round 2
// 29.910 us; speedup vs baseline: 3.2269x; 3.2269x over previous
//
#include <hip/hip_runtime.h>

#define BATCH 384
#define DIM   1024
#define MARGIN_F 0.5f
#define EPS_F 1e-16f
#define N2 (BATCH * BATCH)

// ---------------------------------------------------------------------------
// Kernel 1: split-K partial squared distances.
// Block (bx,by,bz) computes the 32x32 tile (by,bx) of sum_{k in slice bz}
// (E[i][k]-E[j][k])^2 and writes it to dpart[bz*N2 + ...]. No atomics.
// 2x2 micro-tile per thread -> 4 independent FMA chains for ILP.
// ---------------------------------------------------------------------------
__global__ __launch_bounds__(256) void dist_kernel(const float* __restrict__ E,
                                                   float* __restrict__ dpart,
                                                   int kslice) {
    __shared__ float As[32][33];
    __shared__ float Bs[32][33];

    const int tx = threadIdx.x & 15;
    const int ty = threadIdx.x >> 4;
    const int rb = blockIdx.y * 32;
    const int cb = blockIdx.x * 32;
    const int kb = blockIdx.z * kslice;

    float acc00 = 0.f, acc01 = 0.f, acc10 = 0.f, acc11 = 0.f;

    const int lr = threadIdx.x >> 3;        // 0..31 row within tile
    const int lc = (threadIdx.x & 7) * 4;   // 0,4,...,28

    for (int k0 = 0; k0 < kslice; k0 += 32) {
        float4 av = *(const float4*)&E[(size_t)(rb + lr) * DIM + kb + k0 + lc];
        float4 bv = *(const float4*)&E[(size_t)(cb + lr) * DIM + kb + k0 + lc];
        As[lr][lc + 0] = av.x; As[lr][lc + 1] = av.y;
        As[lr][lc + 2] = av.z; As[lr][lc + 3] = av.w;
        Bs[lr][lc + 0] = bv.x; Bs[lr][lc + 1] = bv.y;
        Bs[lr][lc + 2] = bv.z; Bs[lr][lc + 3] = bv.w;
        __syncthreads();

#pragma unroll
        for (int k = 0; k < 32; ++k) {
            float a0 = As[ty * 2 + 0][k];
            float a1 = As[ty * 2 + 1][k];
            float b0 = Bs[tx * 2 + 0][k];
            float b1 = Bs[tx * 2 + 1][k];
            float t;
            t = a0 - b0; acc00 += t * t;
            t = a0 - b1; acc01 += t * t;
            t = a1 - b0; acc10 += t * t;
            t = a1 - b1; acc11 += t * t;
        }
        __syncthreads();
    }

    float* dst = dpart + (size_t)blockIdx.z * N2;
    const int r0 = rb + ty * 2, c0 = cb + tx * 2;
    dst[(size_t)(r0 + 0) * BATCH + c0 + 0] = acc00;
    dst[(size_t)(r0 + 0) * BATCH + c0 + 1] = acc01;
    dst[(size_t)(r0 + 1) * BATCH + c0 + 0] = acc10;
    dst[(size_t)(r0 + 1) * BATCH + c0 + 1] = acc11;
}

// ---------------------------------------------------------------------------
// Kernel 2: per-anchor triplet reduction.
// Stages drow[i] = sqrt(sum_z dpart[z][a][i]) (exact 0 on the diagonal),
// builds the positives list with a deterministic ballot+prefix-popcount on
// wave 0, then each thread handles strided negatives x all positives.
// Writes per-block partials (no atomics, fully deterministic).
// ---------------------------------------------------------------------------
__global__ __launch_bounds__(256) void triplet_kernel(const float* __restrict__ dpart,
                                                      const int* __restrict__ labels,
                                                      float* __restrict__ part,
                                                      int nslice) {
    __shared__ float drow[BATCH];
    __shared__ int   lab[BATCH];
    __shared__ int   plist[BATCH];
    __shared__ int   npos_s;
    __shared__ float ssum[4];
    __shared__ int   spos[4];
    __shared__ int   sval[4];

    const int t = threadIdx.x;
    const int a = blockIdx.x;

    for (int i = t; i < BATCH; i += 256) {
        float s = 0.f;
        for (int z = 0; z < nslice; ++z)
            s += dpart[(size_t)z * N2 + (size_t)a * BATCH + i];
        drow[i] = s > 0.f ? sqrtf(s) : 0.f;
        lab[i]  = labels[i];
    }
    __syncthreads();

    const int la = lab[a];

    // deterministic positives-list build on wave 0
    if (t < 64) {
        int cnt = 0;
#pragma unroll
        for (int c = 0; c < BATCH; c += 64) {
            const int i = c + t;
            const bool f = (lab[i] == la) && (i != a);
            const unsigned long long m = __ballot(f);
            if (f) {
                const int off = __popcll(m & ((1ull << t) - 1ull));
                plist[cnt + off] = i;
            }
            cnt += __popcll(m);
        }
        if (t == 0) npos_s = cnt;
    }
    __syncthreads();

    const int npos = npos_s;
    float sum = 0.f;
    int   pos = 0, valid = 0;

    for (int n = t; n < BATCH; n += 256) {
        if (lab[n] != la) {
            const float dan = drow[n];
            valid += npos;
            for (int q = 0; q < npos; ++q) {
                float tl = drow[plist[q]] - dan + MARGIN_F;
                if (tl > EPS_F) { sum += tl; ++pos; }
            }
        }
    }

#pragma unroll
    for (int off = 32; off > 0; off >>= 1) {
        sum   += __shfl_down(sum, off);
        pos   += __shfl_down(pos, off);
        valid += __shfl_down(valid, off);
    }
    const int wave = t >> 6, lane = t & 63;
    if (lane == 0) { ssum[wave] = sum; spos[wave] = pos; sval[wave] = valid; }
    __syncthreads();

    if (t == 0) {
        float s = 0.f; int p2 = 0, v = 0;
#pragma unroll
        for (int w = 0; w < 4; ++w) { s += ssum[w]; p2 += spos[w]; v += sval[w]; }
        part[a]             = s;
        part[BATCH + a]     = (float)p2;
        part[2 * BATCH + a] = (float)v;
    }
}

// ---------------------------------------------------------------------------
// Kernel 3: one-wave finalize. Double accumulation of 384 partials.
// ---------------------------------------------------------------------------
__global__ __launch_bounds__(64) void finalize_kernel(const float* __restrict__ part,
                                                      float* __restrict__ out) {
    const int lane = threadIdx.x;
    double s = 0.0, p = 0.0, v = 0.0;
#pragma unroll
    for (int c = 0; c < BATCH; c += 64) {
        s += (double)part[c + lane];
        p += (double)part[BATCH + c + lane];
        v += (double)part[2 * BATCH + c + lane];
    }
#pragma unroll
    for (int off = 32; off > 0; off >>= 1) {
        s += __shfl_down(s, off);
        p += __shfl_down(p, off);
        v += __shfl_down(v, off);
    }
    if (lane == 0) {
        out[0] = (float)(s / (p + 1e-16));
        out[1] = (float)p;
        out[2] = (float)v;
    }
}

extern "C" void kernel_launch(void* const* d_in, const int* in_sizes, int n_in,
                              void* d_out, int out_size, void* d_ws, size_t ws_size,
                              hipStream_t stream) {
    const int*   labels = (const int*)d_in[0];
    const float* E      = (const float*)d_in[1];
    float* out = (float*)d_out;

    // workspace layout: [part: 3*384 floats, pad to 8KB][dpart: S * 384*384 floats]
    float* part  = (float*)d_ws;
    float* dpart = (float*)((char*)d_ws + 8192);

    // pick the largest split-K factor that fits the workspace
    int S = 8;
    while (S > 1 && 8192 + (size_t)S * N2 * sizeof(float) > ws_size) S >>= 1;
    const int kslice = DIM / S;

    dim3 grid(BATCH / 32, BATCH / 32, S);
    dist_kernel<<<grid, 256, 0, stream>>>(E, dpart, kslice);
    triplet_kernel<<<BATCH, 256, 0, stream>>>(dpart, labels, part, S);
    finalize_kernel<<<1, 64, 0, stream>>>(part, out);
}